// Round 6
// baseline (383.078 us; speedup 1.0000x reference)
//
// AttentionPropagation — fused bf16-MFMA flash attention for MI355X (gfx950).
//
// R4 (theory: LDS-read-bound — 16 ds_read_b128/wave-tile for 1 MFMA each;
// 8 waves/CU x 16 reads x ~12cyc ~= 70-85% of the 2315-cyc tile period):
//  * 64 queries/wave (two 32q groups): every K/V fragment ds_read now feeds
//    2 MFMAs -> LDS read traffic per FLOP halved. Grid 256 x 256thr,
//    1 block/CU, 1 wave/SIMD (VGPR ~300), ILP from dual per-group chains.
//  * q2 folded into the bias MFMA (extK gains two 1.0 slots; eq carries
//    q2h/q2l) with a persistent zero C-vector -> kills 32 v_mov/tile.
//  * max3-shaped fmax trees; W-fragment packs shared across both groups.
//  * prep_kv regridded: 256 blocks (32 keys each), ot split across 4 waves.
// Kept from R3: XOR-swizzled K/V LDS staging + reg-prefetch (T14), exp2-domain
// softmax, defer-max, cvt_pk packing, shfl_xor(32) conv8, s_setprio.
// (Second resubmission — R4 and R5 both hit GPU-acquisition timeouts; no data.)

#include <hip/hip_runtime.h>
#include <stdint.h>

#define NB 2
#define N1 4096
#define N2 32768
#define DD 128
#define KT 32
#define NTILES (N1 / KT)
static constexpr float SCLE = 0.1275174306f;         // 128^-0.5 * log2(e)
static constexpr float CNEG = -0.7213475204444817f;  // -0.5 * log2(e)
static constexpr float THR  = 11.5415603f;           // 8 * log2(e) (defer-max)

typedef float f32x16 __attribute__((ext_vector_type(16)));
typedef __bf16 bf16x8v __attribute__((ext_vector_type(8)));
typedef __bf16 bf16x2v __attribute__((ext_vector_type(2)));
typedef unsigned int u32;
typedef unsigned short u16;

union FragU { uint4 u; bf16x8v b; };

__device__ __forceinline__ u16 f2bf(float f) {
  __bf16 h = (__bf16)f;
  return __builtin_bit_cast(u16, h);
}
__device__ __forceinline__ u32 pk2(float lo, float hi) {
  bf16x2v v; v[0] = (__bf16)lo; v[1] = (__bf16)hi;  // v_cvt_pk_bf16_f32
  return __builtin_bit_cast(u32, v);
}
__device__ __forceinline__ float bfhi(float f) { return (float)(__bf16)f; }
__device__ __forceinline__ float m3(float a, float b, float c) {
  return fmaxf(fmaxf(a, b), c);                      // v_max3_f32
}
__device__ __forceinline__ f32x16 MFMA(uint4 a, uint4 b, const f32x16& c) {
  FragU A, B; A.u = a; B.u = b;
  return __builtin_amdgcn_mfma_f32_32x32x16_bf16(A.b, B.b, c, 0, 0, 0);
}
__device__ __forceinline__ uint4 packhi8(float4 a, float4 b) {
  return make_uint4(pk2(a.x, a.y), pk2(a.z, a.w), pk2(b.x, b.y), pk2(b.z, b.w));
}
__device__ __forceinline__ uint4 packlo8(float4 a, float4 b) {
  return make_uint4(pk2(a.x - bfhi(a.x), a.y - bfhi(a.y)),
                    pk2(a.z - bfhi(a.z), a.w - bfhi(a.w)),
                    pk2(b.x - bfhi(b.x), b.y - bfhi(b.y)),
                    pk2(b.z - bfhi(b.z), b.w - bfhi(b.w)));
}
// C-layout 8-chunk -> B-fragment (K=16), partner exchange via shfl_xor(32).
__device__ __forceinline__ uint4 conv8(float a0, float a1, float a2, float a3,
                                       float a4, float a5, float a6, float a7, int h) {
  u32 A0 = pk2(a0, a1), A1 = pk2(a2, a3);
  u32 B0 = pk2(a4, a5), B1 = pk2(a6, a7);
  u32 A0s = (u32)__shfl_xor((int)A0, 32);
  u32 A1s = (u32)__shfl_xor((int)A1, 32);
  u32 B0s = (u32)__shfl_xor((int)B0, 32);
  u32 B1s = (u32)__shfl_xor((int)B1, 32);
  return h ? make_uint4(B0s, B1s, B0, B1) : make_uint4(A0, A1, A0s, A1s);
}

// ---------------------------------------------------------------------------
// prep_kv: 256 blocks x 32 keys; wave w computes output-dim tile ot=w.
// ---------------------------------------------------------------------------
__global__ __launch_bounds__(256) void prep_kv(
    const float* __restrict__ sxyz, const float* __restrict__ sfeat,
    const float* __restrict__ Wk, const float* __restrict__ bk,
    const float* __restrict__ Wv, const float* __restrict__ bv,
    u16* __restrict__ Kws, u16* __restrict__ VTws, u16* __restrict__ EKws) {
  const int tid = threadIdx.x;
  const int l = tid & 63, w = tid >> 6, h = l >> 5, ln = l & 31;
  const int b = blockIdx.x >> 7;             // 128 blocks per batch
  const int kb = (blockIdx.x & 127) * 32;
  const int key = kb + ln;
  const size_t frow = (size_t)(b * N1 + key) * DD;

  uint4 xf[8];
#pragma unroll
  for (int s = 0; s < 8; ++s) {
    const float4* fp = (const float4*)(sfeat + frow + s * 16 + h * 8);
    xf[s] = packhi8(fp[0], fp[1]);
  }
  const float* xp = sxyz + (size_t)(b * N1 + key) * 3;
  float sx = xp[0], sy = xp[1], sz = xp[2];
  uint4 x8 = h ? make_uint4(0, 0, 0, 0)
               : make_uint4(pk2(sx, sy), pk2(sz, 0.f), 0u, 0u);

  f32x16 kacc, vacc;
#pragma unroll
  for (int r = 0; r < 16; ++r) {
    int o = (r & 3) + 8 * (r >> 2) + 4 * h + 32 * w;
    kacc[r] = bk[o];
    vacc[r] = bv[o];
  }

  const int outd = ln + 32 * w;
  const float* wkr = Wk + (size_t)outd * 131;
  const float* wvr = Wv + (size_t)outd * DD;
#pragma unroll
  for (int s = 0; s < 8; ++s) {
    const float* p = wkr + 3 + s * 16 + h * 8;   // feat weights at cols 3..130
    uint4 wa = make_uint4(pk2(p[0], p[1]), pk2(p[2], p[3]),
                          pk2(p[4], p[5]), pk2(p[6], p[7]));
    kacc = MFMA(wa, xf[s], kacc);
    const float4* q = (const float4*)(wvr + s * 16 + h * 8);
    vacc = MFMA(packhi8(q[0], q[1]), xf[s], vacc);
  }
  {
    uint4 w8 = h ? make_uint4(0, 0, 0, 0)
                 : make_uint4(pk2(wkr[0], wkr[1]), pk2(wkr[2], 0.f), 0u, 0u);
    kacc = MFMA(w8, x8, kacc);
  }

#pragma unroll
  for (int rq = 0; rq < 4; ++rq) {
    uint2 kv;
    kv.x = pk2(kacc[rq * 4 + 0], kacc[rq * 4 + 1]);
    kv.y = pk2(kacc[rq * 4 + 2], kacc[rq * 4 + 3]);
    *(uint2*)&Kws[(size_t)(b * N1 + key) * DD + w * 32 + rq * 8 + h * 4] = kv;
  }
#pragma unroll
  for (int r = 0; r < 16; ++r) {
    int o = (r & 3) + 8 * (r >> 2) + 4 * h + 32 * w;
    VTws[(size_t)(b * DD + o) * N1 + key] = f2bf(vacc[r]);
  }

  // extK pairs with extQ: sum = |k|^2 - 2 q.k + |q|^2 (1.0 slots carry q2h/q2l)
  if (tid < 32) {
    int k2i = kb + tid;
    const float* xq = sxyz + (size_t)(b * N1 + k2i) * 3;
    float x = xq[0], y = xq[1], z = xq[2];
    float k2 = x * x + y * y + z * z;
    float xh = bfhi(x), xl = x - xh;
    float yh = bfhi(y), yl = y - yh;
    float zh = bfhi(z), zl = z - zh;
    float k2h = bfhi(k2), k2l = k2 - k2h;
    uint4 e0 = make_uint4(pk2(xh, xl), pk2(xh, yh), pk2(yl, yh), pk2(zh, zl));
    uint4 e1 = make_uint4(pk2(zh, k2h), pk2(k2l, 1.f), pk2(1.f, 0.f), 0u);
    uint4* dst = (uint4*)&EKws[(size_t)(b * N1 + k2i) * 16];
    dst[0] = e0;
    dst[1] = e1;
  }
}

// ---------------------------------------------------------------------------
// attn_fwd: 64 queries/wave (2 groups), fused Q-proj + flash loop + epilogue.
// ---------------------------------------------------------------------------
__global__ __launch_bounds__(256, 1) void attn_fwd(
    const float* __restrict__ dxyz, const float* __restrict__ dfeat,
    const float* __restrict__ Wq, const float* __restrict__ bq,
    const float* __restrict__ Wo, const float* __restrict__ bo,
    const u16* __restrict__ Kws, const u16* __restrict__ VTws,
    const u16* __restrict__ EKws, float* __restrict__ out) {
  __shared__ __align__(16) u16 sm[8192];  // [0,4096): K 32x128 ; [4096,8192): V^T 128x32

  const int tid = threadIdx.x;
  const int l = tid & 63, w = tid >> 6, h = l >> 5, ln = l & 31;
  const int b = blockIdx.x >> 7;
  const int qb = (blockIdx.x & 127) * 256;
  const int bN1 = b * N1;
  size_t qrow[2];
  qrow[0] = (size_t)(b * N2 + qb + w * 64 + ln);
  qrow[1] = qrow[0] + 32;

  // persistent zero accumulator for the bias MFMA C-operand
  f32x16 zf;
#pragma unroll
  for (int r = 0; r < 16; ++r) zf[r] = 0.f;

  // ---- extQ per group (q2 split-folded into the MFMA via extK's 1.0 slots)
  uint4 eq[2];
  float qx[2], qy[2], qz[2];
#pragma unroll
  for (int g = 0; g < 2; ++g) {
    const float* xp = dxyz + qrow[g] * 3;
    float x = xp[0], y = xp[1], z = xp[2];
    float q2 = x * x + y * y + z * z;
    float xh = bfhi(x), xl = x - xh, yh = bfhi(y), yl = y - yh, zh = bfhi(z), zl = z - zh;
    float q2h = bfhi(q2), q2l = q2 - q2h;
    eq[g] = h ? make_uint4(pk2(-2.f * zl, 1.f), pk2(1.f, q2h), pk2(q2l, 0.f), 0u)
              : make_uint4(pk2(-2.f * xh, -2.f * xh), pk2(-2.f * xl, -2.f * yh),
                           pk2(-2.f * yh, -2.f * yl), pk2(-2.f * zh, -2.f * zh));
    qx[g] = x; qy[g] = y; qz[g] = z;
  }

  // ---- Q projection (pre-scaled by SCALE*log2e); W packs shared by groups
  uint4 qf[2][8];
  {
    uint4 xf[2][8], x8[2];
#pragma unroll
    for (int g = 0; g < 2; ++g) {
#pragma unroll
      for (int s = 0; s < 8; ++s) {
        const float4* fp = (const float4*)(dfeat + qrow[g] * DD + s * 16 + h * 8);
        xf[g][s] = packhi8(fp[0], fp[1]);
      }
      x8[g] = h ? make_uint4(0, 0, 0, 0)
                : make_uint4(pk2(qx[g], qy[g]), pk2(qz[g], 0.f), 0u, 0u);
    }
#pragma unroll
    for (int ot = 0; ot < 4; ++ot) {
      f32x16 qt[2];
#pragma unroll
      for (int r = 0; r < 16; ++r) {
        float bqv = SCLE * bq[(r & 3) + 8 * (r >> 2) + 4 * h + 32 * ot];
        qt[0][r] = bqv; qt[1][r] = bqv;
      }
      const float* wqr = Wq + (size_t)(ln + 32 * ot) * 131;
#pragma unroll
      for (int s = 0; s < 8; ++s) {
        const float* p = wqr + 3 + s * 16 + h * 8;
        uint4 wa = make_uint4(pk2(SCLE * p[0], SCLE * p[1]), pk2(SCLE * p[2], SCLE * p[3]),
                              pk2(SCLE * p[4], SCLE * p[5]), pk2(SCLE * p[6], SCLE * p[7]));
        qt[0] = MFMA(wa, xf[0][s], qt[0]);
        qt[1] = MFMA(wa, xf[1][s], qt[1]);
      }
      uint4 w8 = h ? make_uint4(0, 0, 0, 0)
                   : make_uint4(pk2(SCLE * wqr[0], SCLE * wqr[1]), pk2(SCLE * wqr[2], 0.f), 0u, 0u);
      qt[0] = MFMA(w8, x8[0], qt[0]);
      qt[1] = MFMA(w8, x8[1], qt[1]);
#pragma unroll
      for (int g = 0; g < 2; ++g) {
        qf[g][2 * ot] = conv8(qt[g][0], qt[g][1], qt[g][2], qt[g][3],
                              qt[g][4], qt[g][5], qt[g][6], qt[g][7], h);
        qf[g][2 * ot + 1] = conv8(qt[g][8], qt[g][9], qt[g][10], qt[g][11],
                                  qt[g][12], qt[g][13], qt[g][14], qt[g][15], h);
      }
    }
  }

  f32x16 oacc[2][4];
#pragma unroll
  for (int g = 0; g < 2; ++g)
#pragma unroll
    for (int ft = 0; ft < 4; ++ft)
#pragma unroll
      for (int r = 0; r < 16; ++r) oacc[g][ft][r] = 0.f;
  float m[2] = {-1e30f, -1e30f}, lsum[2] = {0.f, 0.f};

  // ---- staging geometry (reg-prefetch, T14) — block-level, tid-based
  const int kr = tid >> 4, kd = tid & 15;
  const int vr = tid >> 2, vd = tid & 3;
  const int kswz = (kd ^ (kr & 7)) * 8;
  const int vswz = (vd ^ ((vr >> 1) & 3)) * 8;
  const int vx = (ln >> 1) & 3;
  const u16* Kb = Kws + (size_t)bN1 * DD;
  const u16* Vb = VTws + (size_t)b * DD * N1;
  uint4 k0g, k1g, v0g, v1g;

#define LOADT(kt)                                                            \
  do {                                                                       \
    k0g = *(const uint4*)&Kb[(size_t)((kt) + kr) * DD + kd * 8];             \
    k1g = *(const uint4*)&Kb[(size_t)((kt) + kr + 16) * DD + kd * 8];        \
    v0g = *(const uint4*)&Vb[(size_t)vr * N1 + (kt) + vd * 8];               \
    v1g = *(const uint4*)&Vb[(size_t)(vr + 64) * N1 + (kt) + vd * 8];        \
  } while (0)
#define WRITET()                                                             \
  do {                                                                       \
    *(uint4*)&sm[kr * 128 + kswz] = k0g;                                     \
    *(uint4*)&sm[(kr + 16) * 128 + kswz] = k1g;                              \
    *(uint4*)&sm[4096 + vr * 32 + vswz] = v0g;                               \
    *(uint4*)&sm[4096 + (vr + 64) * 32 + vswz] = v1g;                        \
  } while (0)

  LOADT(0);
  WRITET();
  uint4 ek = *(const uint4*)&EKws[(size_t)(bN1 + ln) * 16 + h * 8];

  for (int t = 0; t < NTILES; ++t) {
    __syncthreads();
    const bool more = (t + 1 < NTILES);
    if (more) LOADT((t + 1) * KT);

    // ---- bias: sq via MFMA (C = zero; q2 through the 1.0 slots)
    f32x16 sacc[2];
    sacc[0] = MFMA(ek, eq[0], zf);
    sacc[1] = MFMA(ek, eq[1], zf);
#pragma unroll
    for (int g = 0; g < 2; ++g)
#pragma unroll
      for (int r = 0; r < 16; ++r)
        sacc[g][r] = CNEG * __builtin_amdgcn_sqrtf(fmaxf(sacc[g][r], 0.f));

    {
      const int ktn = more ? (t + 1) * KT : 0;
      ek = *(const uint4*)&EKws[(size_t)(bN1 + ktn + ln) * 16 + h * 8];
    }

    // ---- S^T = K·Q^T: 8 shared K-frag reads, 16 MFMAs
    __builtin_amdgcn_s_setprio(1);
#pragma unroll
    for (int kk = 0; kk < 8; ++kk) {
      const uint4 ka = *(const uint4*)&sm[ln * 128 + (((2 * kk + h) ^ (ln & 7)) * 8)];
      sacc[0] = MFMA(ka, qf[0][kk], sacc[0]);
      sacc[1] = MFMA(ka, qf[1][kk], sacc[1]);
    }
    __builtin_amdgcn_s_setprio(0);

    // ---- online softmax per group (exp2 domain)
    uint4 pf[2][2];
#pragma unroll
    for (int g = 0; g < 2; ++g) {
      float a0 = m3(sacc[g][0], sacc[g][1], sacc[g][2]);
      float a1 = m3(sacc[g][3], sacc[g][4], sacc[g][5]);
      float a2 = m3(sacc[g][6], sacc[g][7], sacc[g][8]);
      float a3 = m3(sacc[g][9], sacc[g][10], sacc[g][11]);
      float a4 = m3(sacc[g][12], sacc[g][13], sacc[g][14]);
      float tmax = fmaxf(m3(m3(a0, a1, a2), a3, a4), sacc[g][15]);
      tmax = fmaxf(tmax, __shfl_xor(tmax, 32));
      if (!__all(tmax <= m[g] + THR)) {   // defer-max (T13)
        float nm = fmaxf(m[g], tmax);
        float f = __builtin_amdgcn_exp2f(m[g] - nm);
        lsum[g] *= f;
#pragma unroll
        for (int ft = 0; ft < 4; ++ft)
#pragma unroll
          for (int r = 0; r < 16; ++r) oacc[g][ft][r] *= f;
        m[g] = nm;
      }
#pragma unroll
      for (int r = 0; r < 16; ++r)
        sacc[g][r] = __builtin_amdgcn_exp2f(sacc[g][r] - m[g]);
      {
        float s0 = sacc[g][0] + sacc[g][1],   s1 = sacc[g][2] + sacc[g][3];
        float s2 = sacc[g][4] + sacc[g][5],   s3 = sacc[g][6] + sacc[g][7];
        float s4 = sacc[g][8] + sacc[g][9],   s5 = sacc[g][10] + sacc[g][11];
        float s6 = sacc[g][12] + sacc[g][13], s7 = sacc[g][14] + sacc[g][15];
        lsum[g] += (s0 + s1) + (s2 + s3) + ((s4 + s5) + (s6 + s7));
      }
      pf[g][0] = conv8(sacc[g][0], sacc[g][1], sacc[g][2], sacc[g][3],
                       sacc[g][4], sacc[g][5], sacc[g][6], sacc[g][7], h);
      pf[g][1] = conv8(sacc[g][8], sacc[g][9], sacc[g][10], sacc[g][11],
                       sacc[g][12], sacc[g][13], sacc[g][14], sacc[g][15], h);
    }

    // ---- O^T += V^T · P^T: 8 shared V-frag reads, 16 MFMAs
    __builtin_amdgcn_s_setprio(1);
#pragma unroll
    for (int ft = 0; ft < 4; ++ft) {
      const int rr = 32 * ft + ln;
      const uint4 va0 = *(const uint4*)&sm[4096 + rr * 32 + ((h ^ vx) * 8)];
      oacc[0][ft] = MFMA(va0, pf[0][0], oacc[0][ft]);
      oacc[1][ft] = MFMA(va0, pf[1][0], oacc[1][ft]);
      const uint4 va1 = *(const uint4*)&sm[4096 + rr * 32 + (((2 + h) ^ vx) * 8)];
      oacc[0][ft] = MFMA(va1, pf[0][1], oacc[0][ft]);
      oacc[1][ft] = MFMA(va1, pf[1][1], oacc[1][ft]);
    }
    __builtin_amdgcn_s_setprio(0);

    __syncthreads();
    if (more) WRITET();
  }
#undef LOADT
#undef WRITET

  // ---- epilogue: out^T = Wo·(O/l) + Wo_h·feat_h + Wo_h·feat_l + Wo_l·feat_h + bo
#pragma unroll
  for (int g = 0; g < 2; ++g) {
    lsum[g] += __shfl_xor(lsum[g], 32);
    const float inv = 1.f / lsum[g];
#pragma unroll
    for (int ft = 0; ft < 4; ++ft)
#pragma unroll
      for (int r = 0; r < 16; ++r) oacc[g][ft][r] *= inv;
  }

  f32x16 oc[2][4];
#pragma unroll
  for (int g = 0; g < 2; ++g)
#pragma unroll
    for (int ot = 0; ot < 4; ++ot)
#pragma unroll
      for (int r = 0; r < 16; ++r)
        oc[g][ot][r] = bo[(r & 3) + 8 * (r >> 2) + 4 * h + 32 * ot];

#pragma unroll
  for (int s = 0; s < 8; ++s) {
    uint4 pb[2], fh[2], fl[2];
#pragma unroll
    for (int g = 0; g < 2; ++g) {
      const f32x16& c = oacc[g][s >> 1];
      const int br = (s & 1) * 8;
      pb[g] = conv8(c[br + 0], c[br + 1], c[br + 2], c[br + 3],
                    c[br + 4], c[br + 5], c[br + 6], c[br + 7], h);
      const float4* fp = (const float4*)(dfeat + qrow[g] * DD + s * 16 + h * 8);
      const float4 fa = fp[0], fb = fp[1];
      fh[g] = packhi8(fa, fb);
      fl[g] = packlo8(fa, fb);
    }
#pragma unroll
    for (int ot = 0; ot < 4; ++ot) {
      const float4* wp = (const float4*)(Wo + (size_t)(ln + 32 * ot) * DD + s * 16 + h * 8);
      const float4 wa = wp[0], wb = wp[1];
      const uint4 wh = packhi8(wa, wb);
      const uint4 wl = packlo8(wa, wb);
#pragma unroll
      for (int g = 0; g < 2; ++g) {
        oc[g][ot] = MFMA(wh, pb[g], oc[g][ot]);
        oc[g][ot] = MFMA(wh, fh[g], oc[g][ot]);
        oc[g][ot] = MFMA(wh, fl[g], oc[g][ot]);
        oc[g][ot] = MFMA(wl, fh[g], oc[g][ot]);
      }
    }
  }

#pragma unroll
  for (int g = 0; g < 2; ++g) {
    float* orow = out + qrow[g] * DD;
#pragma unroll
    for (int ot = 0; ot < 4; ++ot)
#pragma unroll
      for (int rq = 0; rq < 4; ++rq)
        *(float4*)&orow[ot * 32 + rq * 8 + h * 4] =
            make_float4(oc[g][ot][rq * 4 + 0], oc[g][ot][rq * 4 + 1],
                        oc[g][ot][rq * 4 + 2], oc[g][ot][rq * 4 + 3]);
  }
}

// ---------------------------------------------------------------------------
extern "C" void kernel_launch(void* const* d_in, const int* in_sizes, int n_in,
                              void* d_out, int out_size, void* d_ws, size_t ws_size,
                              hipStream_t stream) {
  const float* sxyz = (const float*)d_in[0];
  const float* sfeat = (const float*)d_in[1];
  const float* dxyz = (const float*)d_in[2];
  const float* dfeat = (const float*)d_in[3];
  const float* Wq = (const float*)d_in[4];
  const float* bq = (const float*)d_in[5];
  const float* Wk = (const float*)d_in[6];
  const float* bk = (const float*)d_in[7];
  const float* Wv = (const float*)d_in[8];
  const float* bv = (const float*)d_in[9];
  const float* Wo = (const float*)d_in[10];
  const float* bo = (const float*)d_in[11];

  u16* Kws = (u16*)d_ws;                                // NB*N1*DD bf16 = 2MB
  u16* VTws = Kws + (size_t)NB * N1 * DD;               // NB*DD*N1 bf16 = 2MB
  u16* EKws = VTws + (size_t)NB * DD * N1;              // NB*N1*16 bf16 = 256KB

  prep_kv<<<dim3(NB * 128), dim3(256), 0, stream>>>(sxyz, sfeat, Wk, bk, Wv, bv,
                                                    Kws, VTws, EKws);
  attn_fwd<<<dim3(NB * 128), dim3(256), 0, stream>>>(dxyz, dfeat, Wq, bq, Wo, bo,
                                                     Kws, VTws, EKws, (float*)d_out);
}

// Round 7
// 356.241 us; speedup vs baseline: 1.0753x; 1.0753x over previous
//
// AttentionPropagation — fused bf16-MFMA flash attention for MI355X (gfx950).
//
// R7 (theory: latency-bound at 1 wave/SIMD — R6 showed BOTH pipes low,
// MfmaUtil 20.5 / VALUBusy 41, 5944 cyc/tile vs 272 cyc MFMA issue):
//  * In-wave software pipeline (T15 analog): PV(t-1) deferred into iter t —
//    independent of bias(t)/QK(t), fills the MFMA pipe while softmax(t) waits.
//    P-fragments (pf) carried across iterations in registers.
//  * K double-buffered + V TRIPLE-buffered in LDS (40KB, 1 block/CU):
//    ONE barrier per tile. V needs depth 3 because iter t writes V(t+1)
//    while PV reads V(t-1) ((t+1)%3 != (t-1)%3; all cross-iter pairs are
//    separated by the single end-of-iter barrier).
//  * At 1 wave/SIMD the full 512-VGPR file is free: pipeline costs ~+48 regs
//    with zero occupancy loss.
// Kept identical from R6 (passed, absmax 0.0156): 64q/wave dual groups,
// q2-folded bias MFMA, XOR swizzles, reg-prefetch staging, exp2 softmax,
// defer-max, cvt_pk, shfl_xor(32) conv8, s_setprio.

#include <hip/hip_runtime.h>
#include <stdint.h>

#define NB 2
#define N1 4096
#define N2 32768
#define DD 128
#define KT 32
#define NTILES (N1 / KT)
static constexpr float SCLE = 0.1275174306f;         // 128^-0.5 * log2(e)
static constexpr float CNEG = -0.7213475204444817f;  // -0.5 * log2(e)
static constexpr float THR  = 11.5415603f;           // 8 * log2(e) (defer-max)

typedef float f32x16 __attribute__((ext_vector_type(16)));
typedef __bf16 bf16x8v __attribute__((ext_vector_type(8)));
typedef __bf16 bf16x2v __attribute__((ext_vector_type(2)));
typedef unsigned int u32;
typedef unsigned short u16;

union FragU { uint4 u; bf16x8v b; };

__device__ __forceinline__ u16 f2bf(float f) {
  __bf16 h = (__bf16)f;
  return __builtin_bit_cast(u16, h);
}
__device__ __forceinline__ u32 pk2(float lo, float hi) {
  bf16x2v v; v[0] = (__bf16)lo; v[1] = (__bf16)hi;  // v_cvt_pk_bf16_f32
  return __builtin_bit_cast(u32, v);
}
__device__ __forceinline__ float bfhi(float f) { return (float)(__bf16)f; }
__device__ __forceinline__ float m3(float a, float b, float c) {
  return fmaxf(fmaxf(a, b), c);                      // v_max3_f32
}
__device__ __forceinline__ f32x16 MFMA(uint4 a, uint4 b, const f32x16& c) {
  FragU A, B; A.u = a; B.u = b;
  return __builtin_amdgcn_mfma_f32_32x32x16_bf16(A.b, B.b, c, 0, 0, 0);
}
__device__ __forceinline__ uint4 packhi8(float4 a, float4 b) {
  return make_uint4(pk2(a.x, a.y), pk2(a.z, a.w), pk2(b.x, b.y), pk2(b.z, b.w));
}
__device__ __forceinline__ uint4 packlo8(float4 a, float4 b) {
  return make_uint4(pk2(a.x - bfhi(a.x), a.y - bfhi(a.y)),
                    pk2(a.z - bfhi(a.z), a.w - bfhi(a.w)),
                    pk2(b.x - bfhi(b.x), b.y - bfhi(b.y)),
                    pk2(b.z - bfhi(b.z), b.w - bfhi(b.w)));
}
// C-layout 8-chunk -> B-fragment (K=16), partner exchange via shfl_xor(32).
__device__ __forceinline__ uint4 conv8(float a0, float a1, float a2, float a3,
                                       float a4, float a5, float a6, float a7, int h) {
  u32 A0 = pk2(a0, a1), A1 = pk2(a2, a3);
  u32 B0 = pk2(a4, a5), B1 = pk2(a6, a7);
  u32 A0s = (u32)__shfl_xor((int)A0, 32);
  u32 A1s = (u32)__shfl_xor((int)A1, 32);
  u32 B0s = (u32)__shfl_xor((int)B0, 32);
  u32 B1s = (u32)__shfl_xor((int)B1, 32);
  return h ? make_uint4(B0s, B1s, B0, B1) : make_uint4(A0, A1, A0s, A1s);
}

// ---------------------------------------------------------------------------
// prep_kv: 256 blocks x 32 keys; wave w computes output-dim tile ot=w.
// ---------------------------------------------------------------------------
__global__ __launch_bounds__(256) void prep_kv(
    const float* __restrict__ sxyz, const float* __restrict__ sfeat,
    const float* __restrict__ Wk, const float* __restrict__ bk,
    const float* __restrict__ Wv, const float* __restrict__ bv,
    u16* __restrict__ Kws, u16* __restrict__ VTws, u16* __restrict__ EKws) {
  const int tid = threadIdx.x;
  const int l = tid & 63, w = tid >> 6, h = l >> 5, ln = l & 31;
  const int b = blockIdx.x >> 7;             // 128 blocks per batch
  const int kb = (blockIdx.x & 127) * 32;
  const int key = kb + ln;
  const size_t frow = (size_t)(b * N1 + key) * DD;

  uint4 xf[8];
#pragma unroll
  for (int s = 0; s < 8; ++s) {
    const float4* fp = (const float4*)(sfeat + frow + s * 16 + h * 8);
    xf[s] = packhi8(fp[0], fp[1]);
  }
  const float* xp = sxyz + (size_t)(b * N1 + key) * 3;
  float sx = xp[0], sy = xp[1], sz = xp[2];
  uint4 x8 = h ? make_uint4(0, 0, 0, 0)
               : make_uint4(pk2(sx, sy), pk2(sz, 0.f), 0u, 0u);

  f32x16 kacc, vacc;
#pragma unroll
  for (int r = 0; r < 16; ++r) {
    int o = (r & 3) + 8 * (r >> 2) + 4 * h + 32 * w;
    kacc[r] = bk[o];
    vacc[r] = bv[o];
  }

  const int outd = ln + 32 * w;
  const float* wkr = Wk + (size_t)outd * 131;
  const float* wvr = Wv + (size_t)outd * DD;
#pragma unroll
  for (int s = 0; s < 8; ++s) {
    const float* p = wkr + 3 + s * 16 + h * 8;   // feat weights at cols 3..130
    uint4 wa = make_uint4(pk2(p[0], p[1]), pk2(p[2], p[3]),
                          pk2(p[4], p[5]), pk2(p[6], p[7]));
    kacc = MFMA(wa, xf[s], kacc);
    const float4* q = (const float4*)(wvr + s * 16 + h * 8);
    vacc = MFMA(packhi8(q[0], q[1]), xf[s], vacc);
  }
  {
    uint4 w8 = h ? make_uint4(0, 0, 0, 0)
                 : make_uint4(pk2(wkr[0], wkr[1]), pk2(wkr[2], 0.f), 0u, 0u);
    kacc = MFMA(w8, x8, kacc);
  }

#pragma unroll
  for (int rq = 0; rq < 4; ++rq) {
    uint2 kv;
    kv.x = pk2(kacc[rq * 4 + 0], kacc[rq * 4 + 1]);
    kv.y = pk2(kacc[rq * 4 + 2], kacc[rq * 4 + 3]);
    *(uint2*)&Kws[(size_t)(b * N1 + key) * DD + w * 32 + rq * 8 + h * 4] = kv;
  }
#pragma unroll
  for (int r = 0; r < 16; ++r) {
    int o = (r & 3) + 8 * (r >> 2) + 4 * h + 32 * w;
    VTws[(size_t)(b * DD + o) * N1 + key] = f2bf(vacc[r]);
  }

  // extK pairs with extQ: sum = |k|^2 - 2 q.k + |q|^2 (1.0 slots carry q2h/q2l)
  if (tid < 32) {
    int k2i = kb + tid;
    const float* xq = sxyz + (size_t)(b * N1 + k2i) * 3;
    float x = xq[0], y = xq[1], z = xq[2];
    float k2 = x * x + y * y + z * z;
    float xh = bfhi(x), xl = x - xh;
    float yh = bfhi(y), yl = y - yh;
    float zh = bfhi(z), zl = z - zh;
    float k2h = bfhi(k2), k2l = k2 - k2h;
    uint4 e0 = make_uint4(pk2(xh, xl), pk2(xh, yh), pk2(yl, yh), pk2(zh, zl));
    uint4 e1 = make_uint4(pk2(zh, k2h), pk2(k2l, 1.f), pk2(1.f, 0.f), 0u);
    uint4* dst = (uint4*)&EKws[(size_t)(b * N1 + k2i) * 16];
    dst[0] = e0;
    dst[1] = e1;
  }
}

// ---------------------------------------------------------------------------
// attn_fwd: 64 queries/wave, deferred-PV pipeline, 1 barrier/tile.
// LDS layout (u16 units): K0 [0,4096) K1 [4096,8192) V0/V1/V2 [8192 + i*4096).
// ---------------------------------------------------------------------------
__global__ __launch_bounds__(256, 1) void attn_fwd(
    const float* __restrict__ dxyz, const float* __restrict__ dfeat,
    const float* __restrict__ Wq, const float* __restrict__ bq,
    const float* __restrict__ Wo, const float* __restrict__ bo,
    const u16* __restrict__ Kws, const u16* __restrict__ VTws,
    const u16* __restrict__ EKws, float* __restrict__ out) {
  __shared__ __align__(16) u16 sm[20480];   // 40 KB: 2x K-tile + 3x V-tile

  const int tid = threadIdx.x;
  const int l = tid & 63, w = tid >> 6, h = l >> 5, ln = l & 31;
  const int b = blockIdx.x >> 7;
  const int qb = (blockIdx.x & 127) * 256;
  const int bN1 = b * N1;
  size_t qrow[2];
  qrow[0] = (size_t)(b * N2 + qb + w * 64 + ln);
  qrow[1] = qrow[0] + 32;

  // persistent zero accumulator for the bias MFMA C-operand
  f32x16 zf;
#pragma unroll
  for (int r = 0; r < 16; ++r) zf[r] = 0.f;

  // ---- extQ per group (q2 split-folded into the MFMA via extK's 1.0 slots)
  uint4 eq[2];
  float qx[2], qy[2], qz[2];
#pragma unroll
  for (int g = 0; g < 2; ++g) {
    const float* xp = dxyz + qrow[g] * 3;
    float x = xp[0], y = xp[1], z = xp[2];
    float q2 = x * x + y * y + z * z;
    float xh = bfhi(x), xl = x - xh, yh = bfhi(y), yl = y - yh, zh = bfhi(z), zl = z - zh;
    float q2h = bfhi(q2), q2l = q2 - q2h;
    eq[g] = h ? make_uint4(pk2(-2.f * zl, 1.f), pk2(1.f, q2h), pk2(q2l, 0.f), 0u)
              : make_uint4(pk2(-2.f * xh, -2.f * xh), pk2(-2.f * xl, -2.f * yh),
                           pk2(-2.f * yh, -2.f * yl), pk2(-2.f * zh, -2.f * zh));
    qx[g] = x; qy[g] = y; qz[g] = z;
  }

  // ---- Q projection (pre-scaled by SCALE*log2e); W packs shared by groups
  uint4 qf[2][8];
  {
    uint4 xf[2][8], x8[2];
#pragma unroll
    for (int g = 0; g < 2; ++g) {
#pragma unroll
      for (int s = 0; s < 8; ++s) {
        const float4* fp = (const float4*)(dfeat + qrow[g] * DD + s * 16 + h * 8);
        xf[g][s] = packhi8(fp[0], fp[1]);
      }
      x8[g] = h ? make_uint4(0, 0, 0, 0)
                : make_uint4(pk2(qx[g], qy[g]), pk2(qz[g], 0.f), 0u, 0u);
    }
#pragma unroll
    for (int ot = 0; ot < 4; ++ot) {
      f32x16 qt[2];
#pragma unroll
      for (int r = 0; r < 16; ++r) {
        float bqv = SCLE * bq[(r & 3) + 8 * (r >> 2) + 4 * h + 32 * ot];
        qt[0][r] = bqv; qt[1][r] = bqv;
      }
      const float* wqr = Wq + (size_t)(ln + 32 * ot) * 131;
#pragma unroll
      for (int s = 0; s < 8; ++s) {
        const float* p = wqr + 3 + s * 16 + h * 8;
        uint4 wa = make_uint4(pk2(SCLE * p[0], SCLE * p[1]), pk2(SCLE * p[2], SCLE * p[3]),
                              pk2(SCLE * p[4], SCLE * p[5]), pk2(SCLE * p[6], SCLE * p[7]));
        qt[0] = MFMA(wa, xf[0][s], qt[0]);
        qt[1] = MFMA(wa, xf[1][s], qt[1]);
      }
      uint4 w8 = h ? make_uint4(0, 0, 0, 0)
                   : make_uint4(pk2(SCLE * wqr[0], SCLE * wqr[1]), pk2(SCLE * wqr[2], 0.f), 0u, 0u);
      qt[0] = MFMA(w8, x8[0], qt[0]);
      qt[1] = MFMA(w8, x8[1], qt[1]);
#pragma unroll
      for (int g = 0; g < 2; ++g) {
        qf[g][2 * ot] = conv8(qt[g][0], qt[g][1], qt[g][2], qt[g][3],
                              qt[g][4], qt[g][5], qt[g][6], qt[g][7], h);
        qf[g][2 * ot + 1] = conv8(qt[g][8], qt[g][9], qt[g][10], qt[g][11],
                                  qt[g][12], qt[g][13], qt[g][14], qt[g][15], h);
      }
    }
  }

  f32x16 oacc[2][4];
#pragma unroll
  for (int g = 0; g < 2; ++g)
#pragma unroll
    for (int ft = 0; ft < 4; ++ft)
#pragma unroll
      for (int r = 0; r < 16; ++r) oacc[g][ft][r] = 0.f;
  float m[2] = {-1e30f, -1e30f}, lsum[2] = {0.f, 0.f};

  // ---- staging geometry (reg-prefetch, T14) — block-level, tid-based
  const int kr = tid >> 4, kd = tid & 15;
  const int vr = tid >> 2, vd = tid & 3;
  const int kswz = (kd ^ (kr & 7)) * 8;
  const int vswz = (vd ^ ((vr >> 1) & 3)) * 8;
  const int vx = (ln >> 1) & 3;
  const u16* Kb = Kws + (size_t)bN1 * DD;
  const u16* Vb = VTws + (size_t)b * DD * N1;
  uint4 k0g, k1g, v0g, v1g;

#define LOADT(kt)                                                            \
  do {                                                                       \
    k0g = *(const uint4*)&Kb[(size_t)((kt) + kr) * DD + kd * 8];             \
    k1g = *(const uint4*)&Kb[(size_t)((kt) + kr + 16) * DD + kd * 8];        \
    v0g = *(const uint4*)&Vb[(size_t)vr * N1 + (kt) + vd * 8];               \
    v1g = *(const uint4*)&Vb[(size_t)(vr + 64) * N1 + (kt) + vd * 8];        \
  } while (0)
#define WRITET(kb_, vb_)                                                     \
  do {                                                                       \
    *(uint4*)&sm[(kb_) + kr * 128 + kswz] = k0g;                             \
    *(uint4*)&sm[(kb_) + (kr + 16) * 128 + kswz] = k1g;                      \
    *(uint4*)&sm[(vb_) + vr * 32 + vswz] = v0g;                              \
    *(uint4*)&sm[(vb_) + (vr + 64) * 32 + vswz] = v1g;                       \
  } while (0)

  // prologue: tile 0 staged to K0/V0; tile 1 loads in flight
  LOADT(0);
  WRITET(0, 8192);
  LOADT(KT);
  uint4 ek = *(const uint4*)&EKws[(size_t)(bN1 + ln) * 16 + h * 8];
  __syncthreads();

  uint4 pf[2][2];            // P fragments of tile t-1 (carried across iters)
  int vr3 = 2, vw3 = 1;      // (t-1)%3, (t+1)%3 at t=0

  for (int t = 0; t < NTILES; ++t) {
    // --- stage tile t+1 into the other K buffer / next V buffer
    if (t + 1 < NTILES) WRITET(((t + 1) & 1) * 4096, 8192 + vw3 * 4096);

    // --- bias(t): sq via MFMA (C = zero; q2 through the 1.0 slots) -> sqrt
    f32x16 sacc[2];
    sacc[0] = MFMA(ek, eq[0], zf);
    sacc[1] = MFMA(ek, eq[1], zf);
#pragma unroll
    for (int g = 0; g < 2; ++g)
#pragma unroll
      for (int r = 0; r < 16; ++r)
        sacc[g][r] = CNEG * __builtin_amdgcn_sqrtf(fmaxf(sacc[g][r], 0.f));

    // --- issue global loads for tile t+2
    if (t + 2 < NTILES) LOADT((t + 2) * KT);
    {
      const int ktn = (t + 1 < NTILES) ? (t + 1) * KT : 0;
      ek = *(const uint4*)&EKws[(size_t)(bN1 + ktn + ln) * 16 + h * 8];
    }

    __builtin_amdgcn_s_setprio(1);
    // --- PV(t-1): 16 MFMAs, independent of bias/QK(t) — fills the MFMA pipe
    if (t > 0) {
      const int vbr = 8192 + vr3 * 4096;
#pragma unroll
      for (int ft = 0; ft < 4; ++ft) {
        const int rr = 32 * ft + ln;
        const uint4 va0 = *(const uint4*)&sm[vbr + rr * 32 + ((h ^ vx) * 8)];
        oacc[0][ft] = MFMA(va0, pf[0][0], oacc[0][ft]);
        oacc[1][ft] = MFMA(va0, pf[1][0], oacc[1][ft]);
        const uint4 va1 = *(const uint4*)&sm[vbr + rr * 32 + (((2 + h) ^ vx) * 8)];
        oacc[0][ft] = MFMA(va1, pf[0][1], oacc[0][ft]);
        oacc[1][ft] = MFMA(va1, pf[1][1], oacc[1][ft]);
      }
    }

    // --- QK(t): 8 shared K-frag reads, 16 MFMAs (C = bias)
    {
      const int kbr = (t & 1) * 4096;
#pragma unroll
      for (int kk = 0; kk < 8; ++kk) {
        const uint4 ka = *(const uint4*)&sm[kbr + ln * 128 + (((2 * kk + h) ^ (ln & 7)) * 8)];
        sacc[0] = MFMA(ka, qf[0][kk], sacc[0]);
        sacc[1] = MFMA(ka, qf[1][kk], sacc[1]);
      }
    }
    __builtin_amdgcn_s_setprio(0);

    // --- online softmax(t) (rescale sees oacc incl. PV(t-1)) + conv8 -> pf
#pragma unroll
    for (int g = 0; g < 2; ++g) {
      float a0 = m3(sacc[g][0], sacc[g][1], sacc[g][2]);
      float a1 = m3(sacc[g][3], sacc[g][4], sacc[g][5]);
      float a2 = m3(sacc[g][6], sacc[g][7], sacc[g][8]);
      float a3 = m3(sacc[g][9], sacc[g][10], sacc[g][11]);
      float a4 = m3(sacc[g][12], sacc[g][13], sacc[g][14]);
      float tmax = fmaxf(m3(m3(a0, a1, a2), a3, a4), sacc[g][15]);
      tmax = fmaxf(tmax, __shfl_xor(tmax, 32));
      if (!__all(tmax <= m[g] + THR)) {   // defer-max (T13)
        float nm = fmaxf(m[g], tmax);
        float f = __builtin_amdgcn_exp2f(m[g] - nm);
        lsum[g] *= f;
#pragma unroll
        for (int ft = 0; ft < 4; ++ft)
#pragma unroll
          for (int r = 0; r < 16; ++r) oacc[g][ft][r] *= f;
        m[g] = nm;
      }
#pragma unroll
      for (int r = 0; r < 16; ++r)
        sacc[g][r] = __builtin_amdgcn_exp2f(sacc[g][r] - m[g]);
      {
        float s0 = sacc[g][0] + sacc[g][1],   s1 = sacc[g][2] + sacc[g][3];
        float s2 = sacc[g][4] + sacc[g][5],   s3 = sacc[g][6] + sacc[g][7];
        float s4 = sacc[g][8] + sacc[g][9],   s5 = sacc[g][10] + sacc[g][11];
        float s6 = sacc[g][12] + sacc[g][13], s7 = sacc[g][14] + sacc[g][15];
        lsum[g] += (s0 + s1) + (s2 + s3) + ((s4 + s5) + (s6 + s7));
      }
      pf[g][0] = conv8(sacc[g][0], sacc[g][1], sacc[g][2], sacc[g][3],
                       sacc[g][4], sacc[g][5], sacc[g][6], sacc[g][7], h);
      pf[g][1] = conv8(sacc[g][8], sacc[g][9], sacc[g][10], sacc[g][11],
                       sacc[g][12], sacc[g][13], sacc[g][14], sacc[g][15], h);
    }

    __syncthreads();                       // single barrier per tile
    vr3 = (vr3 == 2) ? 0 : vr3 + 1;
    vw3 = (vw3 == 2) ? 0 : vw3 + 1;
  }

  // --- drain: PV(NTILES-1)
  {
    const int vbr = 8192 + vr3 * 4096;     // vr3 == (NTILES-1)%3 here
#pragma unroll
    for (int ft = 0; ft < 4; ++ft) {
      const int rr = 32 * ft + ln;
      const uint4 va0 = *(const uint4*)&sm[vbr + rr * 32 + ((h ^ vx) * 8)];
      oacc[0][ft] = MFMA(va0, pf[0][0], oacc[0][ft]);
      oacc[1][ft] = MFMA(va0, pf[1][0], oacc[1][ft]);
      const uint4 va1 = *(const uint4*)&sm[vbr + rr * 32 + (((2 + h) ^ vx) * 8)];
      oacc[0][ft] = MFMA(va1, pf[0][1], oacc[0][ft]);
      oacc[1][ft] = MFMA(va1, pf[1][1], oacc[1][ft]);
    }
  }
#undef LOADT
#undef WRITET

  // ---- epilogue: out^T = Wo·(O/l) + Wo_h·feat_h + Wo_h·feat_l + Wo_l·feat_h + bo
#pragma unroll
  for (int g = 0; g < 2; ++g) {
    lsum[g] += __shfl_xor(lsum[g], 32);
    const float inv = 1.f / lsum[g];
#pragma unroll
    for (int ft = 0; ft < 4; ++ft)
#pragma unroll
      for (int r = 0; r < 16; ++r) oacc[g][ft][r] *= inv;
  }

  f32x16 oc[2][4];
#pragma unroll
  for (int g = 0; g < 2; ++g)
#pragma unroll
    for (int ot = 0; ot < 4; ++ot)
#pragma unroll
      for (int r = 0; r < 16; ++r)
        oc[g][ot][r] = bo[(r & 3) + 8 * (r >> 2) + 4 * h + 32 * ot];

#pragma unroll
  for (int s = 0; s < 8; ++s) {
    uint4 pb[2], fh[2], fl[2];
#pragma unroll
    for (int g = 0; g < 2; ++g) {
      const f32x16& c = oacc[g][s >> 1];
      const int br = (s & 1) * 8;
      pb[g] = conv8(c[br + 0], c[br + 1], c[br + 2], c[br + 3],
                    c[br + 4], c[br + 5], c[br + 6], c[br + 7], h);
      const float4* fp = (const float4*)(dfeat + qrow[g] * DD + s * 16 + h * 8);
      const float4 fa = fp[0], fb = fp[1];
      fh[g] = packhi8(fa, fb);
      fl[g] = packlo8(fa, fb);
    }
#pragma unroll
    for (int ot = 0; ot < 4; ++ot) {
      const float4* wp = (const float4*)(Wo + (size_t)(ln + 32 * ot) * DD + s * 16 + h * 8);
      const float4 wa = wp[0], wb = wp[1];
      const uint4 wh = packhi8(wa, wb);
      const uint4 wl = packlo8(wa, wb);
#pragma unroll
      for (int g = 0; g < 2; ++g) {
        oc[g][ot] = MFMA(wh, pb[g], oc[g][ot]);
        oc[g][ot] = MFMA(wh, fh[g], oc[g][ot]);
        oc[g][ot] = MFMA(wh, fl[g], oc[g][ot]);
        oc[g][ot] = MFMA(wl, fh[g], oc[g][ot]);
      }
    }
  }

#pragma unroll
  for (int g = 0; g < 2; ++g) {
    float* orow = out + qrow[g] * DD;
#pragma unroll
    for (int ot = 0; ot < 4; ++ot)
#pragma unroll
      for (int rq = 0; rq < 4; ++rq)
        *(float4*)&orow[ot * 32 + rq * 8 + h * 4] =
            make_float4(oc[g][ot][rq * 4 + 0], oc[g][ot][rq * 4 + 1],
                        oc[g][ot][rq * 4 + 2], oc[g][ot][rq * 4 + 3]);
  }
}

// ---------------------------------------------------------------------------
extern "C" void kernel_launch(void* const* d_in, const int* in_sizes, int n_in,
                              void* d_out, int out_size, void* d_ws, size_t ws_size,
                              hipStream_t stream) {
  const float* sxyz = (const float*)d_in[0];
  const float* sfeat = (const float*)d_in[1];
  const float* dxyz = (const float*)d_in[2];
  const float* dfeat = (const float*)d_in[3];
  const float* Wq = (const float*)d_in[4];
  const float* bq = (const float*)d_in[5];
  const float* Wk = (const float*)d_in[6];
  const float* bk = (const float*)d_in[7];
  const float* Wv = (const float*)d_in[8];
  const float* bv = (const float*)d_in[9];
  const float* Wo = (const float*)d_in[10];
  const float* bo = (const float*)d_in[11];

  u16* Kws = (u16*)d_ws;                                // NB*N1*DD bf16 = 2MB
  u16* VTws = Kws + (size_t)NB * N1 * DD;               // NB*DD*N1 bf16 = 2MB
  u16* EKws = VTws + (size_t)NB * DD * N1;              // NB*N1*16 bf16 = 256KB

  prep_kv<<<dim3(NB * 128), dim3(256), 0, stream>>>(sxyz, sfeat, Wk, bk, Wv, bv,
                                                    Kws, VTws, EKws);
  attn_fwd<<<dim3(NB * 128), dim3(256), 0, stream>>>(dxyz, dfeat, Wq, bq, Wo, bo,
                                                     Kws, VTws, EKws, (float*)d_out);
}